// Round 6
// baseline (127.294 us; speedup 1.0000x reference)
//
#include <hip/hip_runtime.h>

// i1e(x) = exp(-x)*I1(x) for x in [0.1, 100] (inputs strictly positive).
//
// z <= 8 : i1e = z * Q(z^2) * exp2(-z*log2e - 1), Q = Taylor of I1(z)/(z/2)
//          truncated at k=8. Trunc err ~1.4e-4 abs at z=8.
// z >  8 : i1e = P(1/z) * rsqrt(z), deg-4, 1/sqrt(2*pi) folded in.
//          Err ~5e-6 abs.
// Comparison floor is bf16 quantum (~9.8e-4); threshold 4.375e-3 absolute.
//
// R6: NT hints RESTORED (R5 proved they're worth ~12%); MLP depth 4 -> 8
// independent float4 chunks per iteration (single variable vs R4).

typedef float v4f __attribute__((ext_vector_type(4)));

__device__ __forceinline__ float i1e_one(float z) {
    // ---- small branch: z <= 8 (Taylor, deg-8 Horner in w = z^2) ----
    float w = z * z;
    float q = 1.0427930e-15f;
    q = __fmaf_rn(q, w, 3.0035206e-13f);
    q = __fmaf_rn(q, w, 6.7278617e-11f);
    q = __fmaf_rn(q, w, 1.1302806e-8f);
    q = __fmaf_rn(q, w, 1.3563368e-6f);
    q = __fmaf_rn(q, w, 1.0850694e-4f);
    q = __fmaf_rn(q, w, 5.2083335e-3f);
    q = __fmaf_rn(q, w, 0.125f);
    q = __fmaf_rn(q, w, 1.0f);
    // 0.5*exp(-z) = exp2(-z*log2(e) - 1); v_exp_f32 computes 2^x
    float e  = __builtin_amdgcn_exp2f(__fmaf_rn(z, -1.44269504f, -1.0f));
    float small = z * q * e;

    // ---- large branch: z > 8 (asymptotic deg-4, 1/sqrt(2pi) folded in) ----
    float r = __frsqrt_rn(z);        // v_rsq_f32
    float u = r * r;                 // ~1/z, no divide
    float p = -0.057527543f;
    p = __fmaf_rn(p, u, -0.040907327f);
    p = __fmaf_rn(p, u, -0.046750878f);
    p = __fmaf_rn(p, u, -0.14960336f);
    p = __fmaf_rn(p, u,  0.39894228f);
    float large = p * r;

    return (z <= 8.0f) ? small : large;
}

__device__ __forceinline__ v4f i1e_v4(v4f v) {
    v4f o;
    o.x = i1e_one(v.x);
    o.y = i1e_one(v.y);
    o.z = i1e_one(v.z);
    o.w = i1e_one(v.w);
    return o;
}

__global__ void __launch_bounds__(256, 8)
ive_kernel(const float* __restrict__ in, float* __restrict__ out, int n4, int n) {
    int tid    = blockIdx.x * blockDim.x + threadIdx.x;
    int stride = gridDim.x * blockDim.x;

    const v4f* in4  = reinterpret_cast<const v4f*>(in);
    v4f*       out4 = reinterpret_cast<v4f*>(out);

    int i = tid;
    // main loop: 8 independent float4 chunks in flight per iteration
    for (; i + 7 * stride < n4; i += 8 * stride) {
        v4f a0 = __builtin_nontemporal_load(in4 + i);
        v4f a1 = __builtin_nontemporal_load(in4 + i + stride);
        v4f a2 = __builtin_nontemporal_load(in4 + i + 2 * stride);
        v4f a3 = __builtin_nontemporal_load(in4 + i + 3 * stride);
        v4f a4 = __builtin_nontemporal_load(in4 + i + 4 * stride);
        v4f a5 = __builtin_nontemporal_load(in4 + i + 5 * stride);
        v4f a6 = __builtin_nontemporal_load(in4 + i + 6 * stride);
        v4f a7 = __builtin_nontemporal_load(in4 + i + 7 * stride);
        __builtin_nontemporal_store(i1e_v4(a0), out4 + i);
        __builtin_nontemporal_store(i1e_v4(a1), out4 + i + stride);
        __builtin_nontemporal_store(i1e_v4(a2), out4 + i + 2 * stride);
        __builtin_nontemporal_store(i1e_v4(a3), out4 + i + 3 * stride);
        __builtin_nontemporal_store(i1e_v4(a4), out4 + i + 4 * stride);
        __builtin_nontemporal_store(i1e_v4(a5), out4 + i + 5 * stride);
        __builtin_nontemporal_store(i1e_v4(a6), out4 + i + 6 * stride);
        __builtin_nontemporal_store(i1e_v4(a7), out4 + i + 7 * stride);
    }
    // cleanup: remaining float4s
    for (; i < n4; i += stride) {
        v4f a = __builtin_nontemporal_load(in4 + i);
        __builtin_nontemporal_store(i1e_v4(a), out4 + i);
    }
    // scalar tail (n not divisible by 4)
    for (int j = 4 * n4 + tid; j < n; j += stride) {
        out[j] = i1e_one(in[j]);
    }
}

extern "C" void kernel_launch(void* const* d_in, const int* in_sizes, int n_in,
                              void* d_out, int out_size, void* d_ws, size_t ws_size,
                              hipStream_t stream) {
    const float* z   = (const float*)d_in[0];
    float*       out = (float*)d_out;
    int n  = in_sizes[0];
    int n4 = n >> 2;

    int block = 256;
    int grid  = 2048;                 // 256 CU x 8 blocks/CU, exactly resident
    int need  = (n4 + 8 * block - 1) / (8 * block);
    if (grid > need) grid = need;
    if (grid < 1) grid = 1;

    ive_kernel<<<grid, block, 0, stream>>>(z, out, n4, n);
}

// Round 7
// 112.629 us; speedup vs baseline: 1.1302x; 1.1302x over previous
//
#include <hip/hip_runtime.h>

// i1e(x) = exp(-x)*I1(x) for x in [0.1, 100] (inputs strictly positive).
//
// z <= 8 : i1e = z * Q(z^2) * exp2(-z*log2e - 1), Q = Taylor of I1(z)/(z/2)
//          truncated at k=8. Trunc err ~1.4e-4 abs at z=8.
// z >  8 : i1e = P(1/z) * rsqrt(z), deg-4, 1/sqrt(2*pi) folded in.
//          Err ~5e-6 abs.
// Comparison floor is bf16 quantum (~9.8e-4); threshold 4.375e-3 absolute.
//
// R7: single variable vs R4 (NT + depth 4 = 105us): explicit cross-iteration
// software pipeline — prefetch iteration k+1's 4 chunks BEFORE compute+store
// of iteration k, so each load has ~a full iteration of lead time instead of
// being consumed right after issue.

typedef float v4f __attribute__((ext_vector_type(4)));

__device__ __forceinline__ float i1e_one(float z) {
    // ---- small branch: z <= 8 (Taylor, deg-8 Horner in w = z^2) ----
    float w = z * z;
    float q = 1.0427930e-15f;
    q = __fmaf_rn(q, w, 3.0035206e-13f);
    q = __fmaf_rn(q, w, 6.7278617e-11f);
    q = __fmaf_rn(q, w, 1.1302806e-8f);
    q = __fmaf_rn(q, w, 1.3563368e-6f);
    q = __fmaf_rn(q, w, 1.0850694e-4f);
    q = __fmaf_rn(q, w, 5.2083335e-3f);
    q = __fmaf_rn(q, w, 0.125f);
    q = __fmaf_rn(q, w, 1.0f);
    // 0.5*exp(-z) = exp2(-z*log2(e) - 1); v_exp_f32 computes 2^x
    float e  = __builtin_amdgcn_exp2f(__fmaf_rn(z, -1.44269504f, -1.0f));
    float small = z * q * e;

    // ---- large branch: z > 8 (asymptotic deg-4, 1/sqrt(2pi) folded in) ----
    float r = __frsqrt_rn(z);        // v_rsq_f32
    float u = r * r;                 // ~1/z, no divide
    float p = -0.057527543f;
    p = __fmaf_rn(p, u, -0.040907327f);
    p = __fmaf_rn(p, u, -0.046750878f);
    p = __fmaf_rn(p, u, -0.14960336f);
    p = __fmaf_rn(p, u,  0.39894228f);
    float large = p * r;

    return (z <= 8.0f) ? small : large;
}

__device__ __forceinline__ v4f i1e_v4(v4f v) {
    v4f o;
    o.x = i1e_one(v.x);
    o.y = i1e_one(v.y);
    o.z = i1e_one(v.z);
    o.w = i1e_one(v.w);
    return o;
}

__global__ void __launch_bounds__(256, 8)
ive_kernel(const float* __restrict__ in, float* __restrict__ out, int n4, int n) {
    int tid    = blockIdx.x * blockDim.x + threadIdx.x;
    int stride = gridDim.x * blockDim.x;

    const v4f* in4  = reinterpret_cast<const v4f*>(in);
    v4f*       out4 = reinterpret_cast<v4f*>(out);

    int i = tid;
    if (i + 3 * stride < n4) {
        // prologue: load iteration 0
        v4f a0 = __builtin_nontemporal_load(in4 + i);
        v4f a1 = __builtin_nontemporal_load(in4 + i + stride);
        v4f a2 = __builtin_nontemporal_load(in4 + i + 2 * stride);
        v4f a3 = __builtin_nontemporal_load(in4 + i + 3 * stride);

        // steady state: prefetch iter k+1, then compute+store iter k
        for (; i + 7 * stride < n4; i += 4 * stride) {
            int j = i + 4 * stride;
            v4f b0 = __builtin_nontemporal_load(in4 + j);
            v4f b1 = __builtin_nontemporal_load(in4 + j + stride);
            v4f b2 = __builtin_nontemporal_load(in4 + j + 2 * stride);
            v4f b3 = __builtin_nontemporal_load(in4 + j + 3 * stride);
            __builtin_nontemporal_store(i1e_v4(a0), out4 + i);
            __builtin_nontemporal_store(i1e_v4(a1), out4 + i + stride);
            __builtin_nontemporal_store(i1e_v4(a2), out4 + i + 2 * stride);
            __builtin_nontemporal_store(i1e_v4(a3), out4 + i + 3 * stride);
            a0 = b0; a1 = b1; a2 = b2; a3 = b3;
        }
        // epilogue: compute+store the last prefetched group
        __builtin_nontemporal_store(i1e_v4(a0), out4 + i);
        __builtin_nontemporal_store(i1e_v4(a1), out4 + i + stride);
        __builtin_nontemporal_store(i1e_v4(a2), out4 + i + 2 * stride);
        __builtin_nontemporal_store(i1e_v4(a3), out4 + i + 3 * stride);
        i += 4 * stride;
    }
    // cleanup: remaining float4s
    for (; i < n4; i += stride) {
        v4f a = __builtin_nontemporal_load(in4 + i);
        __builtin_nontemporal_store(i1e_v4(a), out4 + i);
    }
    // scalar tail (n not divisible by 4)
    for (int j = 4 * n4 + tid; j < n; j += stride) {
        out[j] = i1e_one(in[j]);
    }
}

extern "C" void kernel_launch(void* const* d_in, const int* in_sizes, int n_in,
                              void* d_out, int out_size, void* d_ws, size_t ws_size,
                              hipStream_t stream) {
    const float* z   = (const float*)d_in[0];
    float*       out = (float*)d_out;
    int n  = in_sizes[0];
    int n4 = n >> 2;

    int block = 256;
    int grid  = 2048;                 // 256 CU x 8 blocks/CU, exactly resident
    int need  = (n4 + 4 * block - 1) / (4 * block);
    if (grid > need) grid = need;
    if (grid < 1) grid = 1;

    ive_kernel<<<grid, block, 0, stream>>>(z, out, n4, n);
}

// Round 8
// 92.135 us; speedup vs baseline: 1.3816x; 1.2224x over previous
//
#include <hip/hip_runtime.h>

// i1e(x) = exp(-x)*I1(x) for x in [0.1, 100] (inputs strictly positive).
//
// z <= 8 : i1e = z * Q(z^2) * exp2(-z*log2e - 1), Q = Taylor of I1(z)/(z/2)
//          truncated at k=8. Trunc err ~1.4e-4 abs at z=8.
// z >  8 : i1e = P(1/z) * rsqrt(z), deg-4, 1/sqrt(2*pi) folded in.
//          Err ~5e-6 abs.
// Comparison floor is bf16 quantum (~9.8e-4); threshold 4.375e-3 absolute.
//
// R8: single variable vs R4 (both-NT, 105us): NT on STORES ONLY.
// Rationale: input (268MB) is marginally larger than L3 (256MB) and is
// re-read every graph replay; NT loads forfeit L3 hits. NT stores keep the
// zero-reuse write stream from evicting the input (R5 showed plain stores
// cost 13us). Quadrants: both-NT=105, none=118, stores-only=THIS.

typedef float v4f __attribute__((ext_vector_type(4)));

__device__ __forceinline__ float i1e_one(float z) {
    // ---- small branch: z <= 8 (Taylor, deg-8 Horner in w = z^2) ----
    float w = z * z;
    float q = 1.0427930e-15f;
    q = __fmaf_rn(q, w, 3.0035206e-13f);
    q = __fmaf_rn(q, w, 6.7278617e-11f);
    q = __fmaf_rn(q, w, 1.1302806e-8f);
    q = __fmaf_rn(q, w, 1.3563368e-6f);
    q = __fmaf_rn(q, w, 1.0850694e-4f);
    q = __fmaf_rn(q, w, 5.2083335e-3f);
    q = __fmaf_rn(q, w, 0.125f);
    q = __fmaf_rn(q, w, 1.0f);
    // 0.5*exp(-z) = exp2(-z*log2(e) - 1); v_exp_f32 computes 2^x
    float e  = __builtin_amdgcn_exp2f(__fmaf_rn(z, -1.44269504f, -1.0f));
    float small = z * q * e;

    // ---- large branch: z > 8 (asymptotic deg-4, 1/sqrt(2pi) folded in) ----
    float r = __frsqrt_rn(z);        // v_rsq_f32
    float u = r * r;                 // ~1/z, no divide
    float p = -0.057527543f;
    p = __fmaf_rn(p, u, -0.040907327f);
    p = __fmaf_rn(p, u, -0.046750878f);
    p = __fmaf_rn(p, u, -0.14960336f);
    p = __fmaf_rn(p, u,  0.39894228f);
    float large = p * r;

    return (z <= 8.0f) ? small : large;
}

__device__ __forceinline__ v4f i1e_v4(v4f v) {
    v4f o;
    o.x = i1e_one(v.x);
    o.y = i1e_one(v.y);
    o.z = i1e_one(v.z);
    o.w = i1e_one(v.w);
    return o;
}

__global__ void __launch_bounds__(256, 8)
ive_kernel(const float* __restrict__ in, float* __restrict__ out, int n4, int n) {
    int tid    = blockIdx.x * blockDim.x + threadIdx.x;
    int stride = gridDim.x * blockDim.x;

    const v4f* in4  = reinterpret_cast<const v4f*>(in);
    v4f*       out4 = reinterpret_cast<v4f*>(out);

    int i = tid;
    // main loop: 4 independent float4 chunks in flight per iteration
    // loads PLAIN (L3-cacheable), stores NONTEMPORAL (bypass L3)
    for (; i + 3 * stride < n4; i += 4 * stride) {
        v4f a = in4[i];
        v4f b = in4[i + stride];
        v4f c = in4[i + 2 * stride];
        v4f d = in4[i + 3 * stride];
        __builtin_nontemporal_store(i1e_v4(a), out4 + i);
        __builtin_nontemporal_store(i1e_v4(b), out4 + i + stride);
        __builtin_nontemporal_store(i1e_v4(c), out4 + i + 2 * stride);
        __builtin_nontemporal_store(i1e_v4(d), out4 + i + 3 * stride);
    }
    // cleanup: remaining float4s
    for (; i < n4; i += stride) {
        v4f a = in4[i];
        __builtin_nontemporal_store(i1e_v4(a), out4 + i);
    }
    // scalar tail (n not divisible by 4)
    for (int j = 4 * n4 + tid; j < n; j += stride) {
        out[j] = i1e_one(in[j]);
    }
}

extern "C" void kernel_launch(void* const* d_in, const int* in_sizes, int n_in,
                              void* d_out, int out_size, void* d_ws, size_t ws_size,
                              hipStream_t stream) {
    const float* z   = (const float*)d_in[0];
    float*       out = (float*)d_out;
    int n  = in_sizes[0];
    int n4 = n >> 2;

    int block = 256;
    int grid  = 2048;                 // 256 CU x 8 blocks/CU, exactly resident
    int need  = (n4 + 4 * block - 1) / (4 * block);
    if (grid > need) grid = need;
    if (grid < 1) grid = 1;

    ive_kernel<<<grid, block, 0, stream>>>(z, out, n4, n);
}